// Round 17
// baseline (526.150 us; speedup 1.0000x reference)
//
#include <hip/hip_runtime.h>
#include <math.h>

#define NEGF -1000000000.0f
#define EPSF 1e-7f

// B=32, T=256, IN=64, H=128, 4H=512, TOP_K=5

typedef float v4f __attribute__((ext_vector_type(4)));
#define FMA4(a, b, c) __builtin_elementwise_fma((a), (b), (c))

// Raw barrier: LDS-only drain + s_barrier (keeps global prefetch in flight).
#define RAWBAR() asm volatile("s_waitcnt lgkmcnt(0)\n\ts_barrier" ::: "memory")

__device__ __forceinline__ float fsigmoid(float x) {
  return 1.0f / (1.0f + __expf(-x));               // overflow -> correct limit
}
__device__ __forceinline__ float ftanh(float x) {
  return 1.0f - 2.0f / (1.0f + __expf(2.0f * x));  // limits +-1: correct
}

// wave64 all-reduce sum via DPP (row_shr 1/2/4/8 + row_bcast 15/31), ~35 cyc.
__device__ __forceinline__ float wave_allsum(float v) {
#if __has_builtin(__builtin_amdgcn_update_dpp) && __has_builtin(__builtin_amdgcn_readlane)
  float f = v;
#define DPPSTEP(ctrl, rmask) { \
    int t = __builtin_amdgcn_update_dpp(0, __builtin_bit_cast(int, f), \
                                        ctrl, rmask, 0xf, true); \
    f += __builtin_bit_cast(float, t); }
  DPPSTEP(0x111, 0xf)   // row_shr:1
  DPPSTEP(0x112, 0xf)   // row_shr:2
  DPPSTEP(0x114, 0xf)   // row_shr:4
  DPPSTEP(0x118, 0xf)   // row_shr:8  -> lane15 of each row has row sum
  DPPSTEP(0x142, 0xa)   // row_bcast:15 into rows 1,3
  DPPSTEP(0x143, 0x8)   // row_bcast:31 into row 3 -> lane 63 = total
#undef DPPSTEP
  return __builtin_bit_cast(float,
      __builtin_amdgcn_readlane(__builtin_bit_cast(int, f), 63));
#else
  for (int off = 1; off < 64; off <<= 1) v += __shfl_xor(v, off, 64);
  return v;
#endif
}

// Kernel 1: xw[b][t][g] = x[b][t] . W_ih[g] + (b_ih[g]+b_hh[g])
// EXACT round-3 version (proven).
__global__ __launch_bounds__(512) void xw_kernel(
    const float* __restrict__ x, const float* __restrict__ W_ih,
    const float* __restrict__ b_ih, const float* __restrict__ b_hh,
    float* __restrict__ xw)
{
  const int t0 = blockIdx.x * 32;
  const int b  = blockIdx.y;
  const int g  = threadIdx.x;

  __shared__ float sx[32 * 64];              // 8 KB
  ((float4*)sx)[threadIdx.x] =
      ((const float4*)(x + (size_t)(b * 256 + t0) * 64))[threadIdx.x];

  const float4* wr = (const float4*)(W_ih + (size_t)g * 64);
  float4 w0 = wr[0],  w1 = wr[1],  w2 = wr[2],  w3 = wr[3],
         w4 = wr[4],  w5 = wr[5],  w6 = wr[6],  w7 = wr[7],
         w8 = wr[8],  w9 = wr[9],  w10 = wr[10], w11 = wr[11],
         w12 = wr[12], w13 = wr[13], w14 = wr[14], w15 = wr[15];
  const float bias = b_ih[g] + b_hh[g];
  __syncthreads();

  float* dst = xw + (size_t)(b * 256 + t0) * 512 + g;
  for (int tt = 0; tt < 32; ++tt) {
    const float4* xr = (const float4*)(sx + tt * 64);
    float a0 = 0.0f, a1 = 0.0f, a2 = 0.0f, a3 = 0.0f;
#define XSTEP(j) { float4 hv = xr[j]; \
    a0 = fmaf(w##j.x, hv.x, a0); a1 = fmaf(w##j.y, hv.y, a1); \
    a2 = fmaf(w##j.z, hv.z, a2); a3 = fmaf(w##j.w, hv.w, a3); }
    XSTEP(0) XSTEP(1) XSTEP(2) XSTEP(3) XSTEP(4) XSTEP(5) XSTEP(6) XSTEP(7)
    XSTEP(8) XSTEP(9) XSTEP(10) XSTEP(11) XSTEP(12) XSTEP(13) XSTEP(14) XSTEP(15)
#undef XSTEP
    dst[(size_t)tt * 512] = (a0 + a1) + (a2 + a3) + bias;
  }
}

// Kernel 2: recurrence with ONE barrier per step, 512 threads (8 waves,
// 2/SIMD). Restructure vs R16 (286us, 2 barriers + 2-wave Phase B):
//
//  * Phase B REPLICATED in all 8 waves (2 elems/lane). All inputs are the
//    shared sh_part and identical deterministic arithmetic -> every wave
//    computes bitwise-identical h. Each wave writes h to its OWN private
//    LDS row (hpriv[wid]) and reads it back in its next Phase A with
//    same-wave lgkmcnt ordering only -> barrier S2 DELETED.
//  * sh_part double-buffered [i&1]: S1(i+1) provably separates Phase B(i)
//    reads of buf0 from Phase A(i+2) writes of buf0.
//  * Top-5 rows' h values CACHED IN REGISTERS (2 floats/lane per slot,
//    shifted along with the (value,index) insert — a row can only enter
//    the top-5 at its creation step, so the cache is complete). The
//    gather is 8 register FMAs: no ho history (128KB LDS deleted; a
//    5-row stub serves the rem<=5 raw path), no prefetch, no race.
//  * a (i<5) and dn computed per-wave via wave_allsum (replicated):
//    sh_pa/sh_dn exchanges and the early extra barrier deleted.
//
// Tripwire: VGPR rises (~170-200: 128 weight floats + h-cache + state);
// WRITE_SIZE must stay 48KB — MBs means spill, revert to R16.
//
// DELTA CANCELLATION (unchanged):
//   s[t] = a + d[t]; delta = a + top5(d)[4] + EPS  =>  w[t] = d[t]-t5v4-EPS
//   independent of a; only the top-4 rows have nonzero weight.
__global__
__attribute__((amdgpu_flat_work_group_size(512, 512), amdgpu_waves_per_eu(2, 2)))
void lstm_attn(
    const float* __restrict__ xw, const float* __restrict__ W_hh,
    const float* __restrict__ w_t, float* __restrict__ out)
{
  const int b   = blockIdx.x;
  const int tid = threadIdx.x;
  const int l   = tid & 63;       // lane
  const int wid = tid >> 6;
  const int g2  = tid & 255;      // gates g2, g2+256
  const int q   = tid >> 8;       // K-half 0/1 (wave-uniform)

  __shared__ float hpriv[8][128];     // per-wave private h row (4 KB)
  __shared__ float sh_part[2][1024];  // gate partials [buf][q*512+gate] (8 KB)
  __shared__ float ho5[5 * 128];      // h rows 0..4 for the rem<=5 raw path
  __shared__ float sh_d[8];           // d[t] cache (raw-score steps)

  // one-time weight load: 2 gate rows x 16 v4f = 32 named v4f
  const v4f* pA = (const v4f*)(W_hh + (size_t)g2 * 128 + (q << 6));
  const v4f* pB = (const v4f*)(W_hh + (size_t)(g2 + 256) * 128 + (q << 6));
  v4f wA0 = pA[0],  wA1 = pA[1],  wA2 = pA[2],  wA3 = pA[3],
      wA4 = pA[4],  wA5 = pA[5],  wA6 = pA[6],  wA7 = pA[7],
      wA8 = pA[8],  wA9 = pA[9],  wA10 = pA[10], wA11 = pA[11],
      wA12 = pA[12], wA13 = pA[13], wA14 = pA[14], wA15 = pA[15];
  v4f wB0 = pB[0],  wB1 = pB[1],  wB2 = pB[2],  wB3 = pB[3],
      wB4 = pB[4],  wB5 = pB[5],  wB6 = pB[6],  wB7 = pB[7],
      wB8 = pB[8],  wB9 = pB[9],  wB10 = pB[10], wB11 = pB[11],
      wB12 = pB[12], wB13 = pB[13], wB14 = pB[14], wB15 = pB[15];

  // per-lane persistent cell state (elements j0=2l, j1=2l+1) — ALL waves
  const int j0 = 2 * l, j1 = 2 * l + 1;
  float cc0 = 0.0f, cc1 = 0.0f;
  const float wa0 = w_t[j0], wa1 = w_t[j1];
  const float wb0 = w_t[128 + j0], wb1 = w_t[128 + j1];
  // top-5 of d with indices AND register-cached h pairs for slots 0..3
  float t5v0 = 0.0f, t5v1 = NEGF, t5v2 = NEGF, t5v3 = NEGF, t5v4 = NEGF;
  int   t5i0 = 0, t5i1 = 0, t5i2 = 0, t5i3 = 0;
  float h5a0 = 0.0f, h5a1 = 0.0f, h5a2 = 0.0f, h5a3 = 0.0f;  // h[j0] per slot
  float h5b0 = 0.0f, h5b1 = 0.0f, h5b2 = 0.0f, h5b3 = 0.0f;  // h[j1] per slot
  float gn0 = 0.0f, gn1 = 0.0f, gn2 = 0.0f, gn3 = 0.0f;

  *(float2*)(&hpriv[wid][j0]) = make_float2(0.0f, 0.0f);   // h(-1) = 0
  if (wid == 0) *(float2*)(ho5 + j0) = make_float2(0.0f, 0.0f);
  if (tid == 0) sh_d[0] = 0.0f;
  __syncthreads();   // one-time full sync

  const float* xwb = xw + (size_t)b * 256 * 512;
  float xcA = 0.0f, xcB = 0.0f;
  if (q == 0) { xcA = xwb[g2]; xcB = xwb[g2 + 256]; }

  for (int i = 0; i < 256; ++i) {
    const int rem = i + 1;

    // ---- Phase A: 2 gate-partials, packed fp32 (32 pk-FMA/thread) ----
    v4f aA = {xcA, 0.0f, 0.0f, 0.0f};
    v4f aB = {xcB, 0.0f, 0.0f, 0.0f};
    if (q == 0 && i < 255) {          // prefetch next step's xw (stays in
      const float* xn = xwb + (size_t)(i + 1) * 512;     // flight over bars)
      xcA = xn[g2]; xcB = xn[g2 + 256];
    }
    const v4f* hh4 = (const v4f*)(&hpriv[wid][q << 6]);
#define KS(k) { v4f hv = hh4[k]; \
    aA = FMA4(wA##k, hv, aA); aB = FMA4(wB##k, hv, aB); }
    KS(0) KS(1) KS(2) KS(3) KS(4) KS(5) KS(6) KS(7)
    KS(8) KS(9) KS(10) KS(11) KS(12) KS(13) KS(14) KS(15)
#undef KS
    {
      float* sp = sh_part[i & 1] + (q << 9) + g2;
      sp[0]   = (aA.x + aA.y) + (aA.z + aA.w);
      sp[256] = (aB.x + aB.y) + (aB.z + aB.w);
    }
    RAWBAR();                                             // S1 (the ONLY barrier)

    // ---- Phase B: LSTM cell, REPLICATED in every wave (2 elems/lane) ----
    const float* s0 = sh_part[i & 1];
    float2 Pi0 = *(const float2*)(s0 + j0);
    float2 Pi1 = *(const float2*)(s0 + 512 + j0);
    float2 Pf0 = *(const float2*)(s0 + 128 + j0);
    float2 Pf1 = *(const float2*)(s0 + 640 + j0);
    float2 Pg0 = *(const float2*)(s0 + 256 + j0);
    float2 Pg1 = *(const float2*)(s0 + 768 + j0);
    float2 Po0 = *(const float2*)(s0 + 384 + j0);
    float2 Po1 = *(const float2*)(s0 + 896 + j0);
    float Pi_x = Pi0.x + Pi1.x, Pi_y = Pi0.y + Pi1.y;
    float Pf_x = Pf0.x + Pf1.x, Pf_y = Pf0.y + Pf1.y;
    float Pg_x = Pg0.x + Pg1.x, Pg_y = Pg0.y + Pg1.y;
    float Po_x = Po0.x + Po1.x, Po_y = Po0.y + Po1.y;
    cc0 = fsigmoid(Pf_x) * cc0 + fsigmoid(Pi_x) * ftanh(Pg_x);
    cc1 = fsigmoid(Pf_y) * cc1 + fsigmoid(Pi_y) * ftanh(Pg_y);
    float hc0 = fsigmoid(Po_x) * ftanh(cc0);
    float hc1 = fsigmoid(Po_y) * ftanh(cc1);

    float at0, at1;
    if (i >= 5) {
      // sparse attention from the REGISTER-cached top-4 rows
      at0 = gn0 * h5a0;            at1 = gn0 * h5b0;
      at0 = fmaf(gn1, h5a1, at0);  at1 = fmaf(gn1, h5b1, at1);
      at0 = fmaf(gn2, h5a2, at0);  at1 = fmaf(gn2, h5b2, at1);
      at0 = fmaf(gn3, h5a3, at0);  at1 = fmaf(gn3, h5b3, at1);
    } else {
      // rem<=5: attn weights are RAW scores s = a + d[t]; a replicated
      float a = wave_allsum(ftanh(hc0) * wa0 + ftanh(hc1) * wa1);
      at0 = 0.0f; at1 = 0.0f;
      for (int t = 0; t <= i; ++t) {
        float s = a + sh_d[t];
        float2 hv = *(const float2*)(ho5 + t * 128 + j0);
        at0 = fmaf(s, hv.x, at0);
        at1 = fmaf(s, hv.y, at1);
      }
    }
    float hn0 = hc0 + at0, hn1 = hc1 + at1;
    *(float2*)(&hpriv[wid][j0]) = make_float2(hn0, hn1);   // own row: no barrier
    if (wid == 0 && rem <= 4)
      *(float2*)(ho5 + rem * 128 + j0) = make_float2(hn0, hn1);
    if (i == 255 && wid == 0) {
      out[b * 128 + j0] = at0; out[b * 128 + j1] = at1;    // attn_c
      // attn_w: zero except at the <=4 above-threshold top-5 indices
      #pragma unroll
      for (int m = 0; m < 4; ++m) {
        int t = l + 64 * m;
        float val = 0.0f;
        if (t == t5i0) val = gn0;
        if (t == t5i1) val = gn1;
        if (t == t5i2) val = gn2;
        if (t == t5i3) val = gn3;
        out[4096 + b * 256 + t] = val;
      }
    }

    // ---- tail: replicated top-5 maintenance (identical in every wave) ----
    if (i < 255) {
      float dn = wave_allsum(ftanh(hn0) * wb0 + ftanh(hn1) * wb1);
      if (wid == 0 && l == 0 && i < 4) sh_d[rem] = dn;
      // insert (dn, rem, hn0, hn1); cached h pairs shift with their slot
      float v = dn; int vi = rem; float va = hn0, vb = hn1;
      if (v > t5v0) { float tv = t5v0; t5v0 = v; v = tv;
                      int   ti = t5i0; t5i0 = vi; vi = ti;
                      float ta = h5a0; h5a0 = va; va = ta;
                      float tb = h5b0; h5b0 = vb; vb = tb; }
      if (v > t5v1) { float tv = t5v1; t5v1 = v; v = tv;
                      int   ti = t5i1; t5i1 = vi; vi = ti;
                      float ta = h5a1; h5a1 = va; va = ta;
                      float tb = h5b1; h5b1 = vb; vb = tb; }
      if (v > t5v2) { float tv = t5v2; t5v2 = v; v = tv;
                      int   ti = t5i2; t5i2 = vi; vi = ti;
                      float ta = h5a2; h5a2 = va; va = ta;
                      float tb = h5b2; h5b2 = vb; vb = tb; }
      if (v > t5v3) { float tv = t5v3; t5v3 = v; v = tv;
                      int   ti = t5i3; t5i3 = vi; vi = ti;
                      float ta = h5a3; h5a3 = va; va = ta;
                      float tb = h5b3; h5b3 = vb; vb = tb; }
      if (v > t5v4) { t5v4 = v; }
      // next step's normalized gather weights (delta cancellation)
      float g0 = fmaxf(t5v0 - t5v4 - EPSF, 0.0f);
      float g1 = fmaxf(t5v1 - t5v4 - EPSF, 0.0f);
      float g2f = fmaxf(t5v2 - t5v4 - EPSF, 0.0f);
      float g3 = fmaxf(t5v3 - t5v4 - EPSF, 0.0f);
      float inv = 1.0f / (((g0 + g1) + (g2f + g3)) + EPSF);
      gn0 = g0 * inv; gn1 = g1 * inv; gn2 = g2f * inv; gn3 = g3 * inv;
    }
  }
}

extern "C" void kernel_launch(void* const* d_in, const int* in_sizes, int n_in,
                              void* d_out, int out_size, void* d_ws, size_t ws_size,
                              hipStream_t stream) {
  const float* x    = (const float*)d_in[0];  // (32,256,64)
  const float* W_ih = (const float*)d_in[1];  // (512,64)
  const float* W_hh = (const float*)d_in[2];  // (512,128)
  const float* b_ih = (const float*)d_in[3];  // (512,)
  const float* b_hh = (const float*)d_in[4];  // (512,)
  const float* w_t  = (const float*)d_in[5];  // (256,1)
  float* out = (float*)d_out;                 // [0:4096) attn_c, [4096:12288) attn_w

  float* xw = (float*)d_ws;                   // 32*256*512 fp32 = 16 MB

  xw_kernel<<<dim3(8, 32), 512, 0, stream>>>(x, W_ih, b_ih, b_hh, xw);
  lstm_attn<<<dim3(32), 512, 0, stream>>>(xw, W_hh, w_t, out);
}